// Round 3
// baseline (739.322 us; speedup 1.0000x reference)
//
#include <hip/hip_runtime.h>

#define N_NODES 100000
#define N_EDGES 1600000
#define N_SCAN_BLOCKS ((N_NODES + 255) / 256)   // 391

// ============ CSR construction (counting sort by dst, atomic-free scatter) ==

// rank[e] = arrival order within dst; cnt[dst] = degree
__global__ __launch_bounds__(256) void k_hist(const int* __restrict__ ei,
                                              int* __restrict__ cnt,
                                              int* __restrict__ rank)
{
    int e = blockIdx.x * 256 + threadIdx.x;
    if (e >= N_EDGES) return;
    rank[e] = atomicAdd(&cnt[ei[N_EDGES + e]], 1);
}

__global__ __launch_bounds__(256) void k_scan_block(const int* __restrict__ cnt,
                                                    int* __restrict__ row_start,
                                                    int* __restrict__ partial)
{
    __shared__ int s[256];
    int i = blockIdx.x * 256 + threadIdx.x;
    int v = (i < N_NODES) ? cnt[i] : 0;
    s[threadIdx.x] = v;
    __syncthreads();
    for (int off = 1; off < 256; off <<= 1) {
        int t = (threadIdx.x >= off) ? s[threadIdx.x - off] : 0;
        __syncthreads();
        s[threadIdx.x] += t;
        __syncthreads();
    }
    if (i < N_NODES) row_start[i] = s[threadIdx.x] - v;   // exclusive
    if (threadIdx.x == 255) partial[blockIdx.x] = s[255]; // block total
}

__global__ __launch_bounds__(512) void k_scan_top(int* __restrict__ partial)
{
    __shared__ int s[512];
    int v = (threadIdx.x < N_SCAN_BLOCKS) ? partial[threadIdx.x] : 0;
    s[threadIdx.x] = v;
    __syncthreads();
    for (int off = 1; off < 512; off <<= 1) {
        int t = (threadIdx.x >= off) ? s[threadIdx.x - off] : 0;
        __syncthreads();
        s[threadIdx.x] += t;
        __syncthreads();
    }
    if (threadIdx.x < N_SCAN_BLOCKS) partial[threadIdx.x] = s[threadIdx.x] - v;
}

__global__ __launch_bounds__(256) void k_scan_add(int* __restrict__ row_start,
                                                 const int* __restrict__ partial)
{
    int i = blockIdx.x * 256 + threadIdx.x;
    if (i < N_NODES) row_start[i] += partial[i >> 8];
    if (i == 0) row_start[N_NODES] = N_EDGES;
}

// pure store, no atomics: position fully determined by row_start + rank
__global__ __launch_bounds__(256) void k_scatter(const int* __restrict__ ei,
                                                 const int* __restrict__ row_start,
                                                 const int* __restrict__ rank,
                                                 int* __restrict__ sorted_src)
{
    int e = blockIdx.x * 256 + threadIdx.x;
    if (e >= N_EDGES) return;
    int dst = ei[N_EDGES + e];
    sorted_src[row_start[dst] + rank[e]] = ei[e];
}

// ============ aggregation: gather-reduce over CSR ============

// one 64-lane wave per node, lane = dim
__global__ __launch_bounds__(256) void k_agg1(const int* __restrict__ row_start,
                                              const int* __restrict__ sorted_src,
                                              const float* __restrict__ x,
                                              float* __restrict__ agg1)
{
    int node = blockIdx.x * 4 + (threadIdx.x >> 6);
    if (node >= N_NODES) return;
    int d = threadIdx.x & 63;
    int beg = row_start[node], end = row_start[node + 1];
    float a0 = 0.0f, a1 = 0.0f;
    int idx = beg;
    for (; idx + 2 <= end; idx += 2) {
        int s0 = sorted_src[idx];
        int s1 = sorted_src[idx + 1];
        a0 += x[(size_t)s0 * 64 + d];
        a1 += x[(size_t)s1 * 64 + d];
    }
    if (idx < end) a0 += x[(size_t)sorted_src[idx] * 64 + d];
    agg1[(size_t)node * 64 + d] = a0 + a1;
}

// 32 lanes per node, lane = dim
__global__ __launch_bounds__(256) void k_agg2(const int* __restrict__ row_start,
                                              const int* __restrict__ sorted_src,
                                              const float* __restrict__ t2,
                                              float* __restrict__ agg2)
{
    int node = blockIdx.x * 8 + (threadIdx.x >> 5);
    if (node >= N_NODES) return;
    int d = threadIdx.x & 31;
    int beg = row_start[node], end = row_start[node + 1];
    float a0 = 0.0f, a1 = 0.0f;
    int idx = beg;
    for (; idx + 2 <= end; idx += 2) {
        int s0 = sorted_src[idx];
        int s1 = sorted_src[idx + 1];
        a0 += t2[(size_t)s0 * 32 + d];
        a1 += t2[(size_t)s1 * 32 + d];
    }
    if (idx < end) a0 += t2[(size_t)sorted_src[idx] * 32 + d];
    agg2[(size_t)node * 32 + d] = a0 + a1;
}

// ============ fused transform: 4 threads per node ============
// h = relu(mean@W1l + x@W1r + b1l)  (each thread: 16 of 64 outputs)
// t2 = h@W2l, t3 = h@W2r            (quad-shuffle reduce, each thread stores 8)
// h itself is never materialized.
__global__ __launch_bounds__(256) void k_xform1(
    const float* __restrict__ x, const float* __restrict__ agg1,
    const int* __restrict__ row_start,
    const float* __restrict__ W1l, const float* __restrict__ b1l,
    const float* __restrict__ W1r, const float* __restrict__ W2l,
    const float* __restrict__ W2r,
    float* __restrict__ t2, float* __restrict__ t3)
{
    int t = blockIdx.x * 256 + threadIdx.x;
    int n = t >> 2;
    if (n >= N_NODES) return;
    int jg = t & 3;                       // output group: j in [jg*16, jg*16+16)
    float degf = (float)(row_start[n + 1] - row_start[n]);
    float inv = 1.0f / fmaxf(degf, 1.0f);

    float acc[16];
#pragma unroll
    for (int jj = 0; jj < 16; jj++) acc[jj] = b1l[jg * 16 + jj];

    const float4* av = (const float4*)(agg1 + (size_t)n * 64);
    const float4* xv = (const float4*)(x + (size_t)n * 64);
    for (int kk = 0; kk < 16; kk++) {
        float4 a4 = av[kk];
        float4 x4 = xv[kk];
        float as[4] = {a4.x * inv, a4.y * inv, a4.z * inv, a4.w * inv};
        float xs[4] = {x4.x, x4.y, x4.z, x4.w};
#pragma unroll
        for (int u = 0; u < 4; u++) {
            int k = kk * 4 + u;
            const float4* wl = (const float4*)(W1l + k * 64 + jg * 16);
            const float4* wr = (const float4*)(W1r + k * 64 + jg * 16);
#pragma unroll
            for (int q = 0; q < 4; q++) {
                float4 l4 = wl[q], r4 = wr[q];
                acc[4*q+0] += as[u] * l4.x + xs[u] * r4.x;
                acc[4*q+1] += as[u] * l4.y + xs[u] * r4.y;
                acc[4*q+2] += as[u] * l4.z + xs[u] * r4.z;
                acc[4*q+3] += as[u] * l4.w + xs[u] * r4.w;
            }
        }
    }

    // relu -> h (16 values in registers), then partial t2/t3 over this thread's j's
    float t2p[32], t3p[32];
#pragma unroll
    for (int o = 0; o < 32; o++) { t2p[o] = 0.0f; t3p[o] = 0.0f; }
#pragma unroll
    for (int jj = 0; jj < 16; jj++) {
        float hj = fmaxf(acc[jj], 0.0f);
        int j = jg * 16 + jj;
        const float4* w2 = (const float4*)(W2l + j * 32);
        const float4* w3 = (const float4*)(W2r + j * 32);
#pragma unroll
        for (int q = 0; q < 8; q++) {
            float4 a = w2[q], b = w3[q];
            t2p[4*q+0] += hj * a.x;  t3p[4*q+0] += hj * b.x;
            t2p[4*q+1] += hj * a.y;  t3p[4*q+1] += hj * b.y;
            t2p[4*q+2] += hj * a.z;  t3p[4*q+2] += hj * b.z;
            t2p[4*q+3] += hj * a.w;  t3p[4*q+3] += hj * b.w;
        }
    }
    // quad reduce (the 4 threads of a node are adjacent lanes)
#pragma unroll
    for (int o = 0; o < 32; o++) {
        t2p[o] += __shfl_xor(t2p[o], 1);
        t2p[o] += __shfl_xor(t2p[o], 2);
        t3p[o] += __shfl_xor(t3p[o], 1);
        t3p[o] += __shfl_xor(t3p[o], 2);
    }
    // each thread writes its 8 elements of t2 and t3
    float4* t2v = (float4*)(t2 + (size_t)n * 32 + jg * 8);
    float4* t3v = (float4*)(t3 + (size_t)n * 32 + jg * 8);
    t2v[0] = make_float4(t2p[jg*8+0], t2p[jg*8+1], t2p[jg*8+2], t2p[jg*8+3]);
    t2v[1] = make_float4(t2p[jg*8+4], t2p[jg*8+5], t2p[jg*8+6], t2p[jg*8+7]);
    t3v[0] = make_float4(t3p[jg*8+0], t3p[jg*8+1], t3p[jg*8+2], t3p[jg*8+3]);
    t3v[1] = make_float4(t3p[jg*8+4], t3p[jg*8+5], t3p[jg*8+6], t3p[jg*8+7]);
}

// ============ output: out = agg2/deg + t3 + b2l (elementwise) ============
__global__ __launch_bounds__(256) void k_out(
    const float* __restrict__ agg2, const float* __restrict__ t3,
    const int* __restrict__ row_start, const float* __restrict__ b2l,
    float* __restrict__ out)
{
    int i = blockIdx.x * 256 + threadIdx.x;          // float4 index
    if (i >= N_NODES * 8) return;
    int n = i >> 3;
    float degf = (float)(row_start[n + 1] - row_start[n]);
    float inv = 1.0f / fmaxf(degf, 1.0f);
    float4 g = ((const float4*)agg2)[i];
    float4 s = ((const float4*)t3)[i];
    float4 b = ((const float4*)b2l)[i & 7];
    ((float4*)out)[i] = make_float4(g.x * inv + s.x + b.x,
                                    g.y * inv + s.y + b.y,
                                    g.z * inv + s.z + b.z,
                                    g.w * inv + s.w + b.w);
}

extern "C" void kernel_launch(void* const* d_in, const int* in_sizes, int n_in,
                              void* d_out, int out_size, void* d_ws, size_t ws_size,
                              hipStream_t stream) {
    const float* x   = (const float*)d_in[0];
    const int*   ei  = (const int*)d_in[1];
    const float* W1l = (const float*)d_in[2];
    const float* b1l = (const float*)d_in[3];
    const float* W1r = (const float*)d_in[4];
    const float* W2l = (const float*)d_in[5];
    const float* b2l = (const float*)d_in[6];
    const float* W2r = (const float*)d_in[7];
    float* out = (float*)d_out;

    const size_t N = N_NODES, E = N_EDGES;
    int* wsi = (int*)d_ws;
    int* cnt        = wsi;                     // N
    int* row_start  = wsi + N;                 // N+1
    int* partial    = wsi + 2 * N + 1;         // 512
    int* rank       = wsi + 2 * N + 513;       // E
    int* sorted_src = wsi + 2 * N + 513 + E;   // E
    float* wsf = (float*)(wsi + 2 * N + 513 + 2 * E);
    float* agg1 = wsf;                         // 64N
    float* agg2 = wsf;                         // 32N (reuses agg1's space)
    float* t2   = wsf + 64 * N;                // 32N
    float* t3   = wsf + 96 * N;                // 32N
    // total: (2N+513+2E)*4 + 128N*4 ~= 65 MB

    hipMemsetAsync(cnt, 0, N * sizeof(int), stream);
    k_hist      <<<(E + 255) / 256, 256, 0, stream>>>(ei, cnt, rank);
    k_scan_block<<<N_SCAN_BLOCKS, 256, 0, stream>>>(cnt, row_start, partial);
    k_scan_top  <<<1, 512, 0, stream>>>(partial);
    k_scan_add  <<<N_SCAN_BLOCKS, 256, 0, stream>>>(row_start, partial);
    k_scatter   <<<(E + 255) / 256, 256, 0, stream>>>(ei, row_start, rank, sorted_src);

    k_agg1  <<<(int)(N / 4), 256, 0, stream>>>(row_start, sorted_src, x, agg1);
    k_xform1<<<(int)((N * 4 + 255) / 256), 256, 0, stream>>>(x, agg1, row_start,
                                                W1l, b1l, W1r, W2l, W2r, t2, t3);
    k_agg2  <<<(int)(N / 8), 256, 0, stream>>>(row_start, sorted_src, t2, agg2);
    k_out   <<<(int)((N * 8 + 255) / 256), 256, 0, stream>>>(agg2, t3, row_start, b2l, out);
}

// Round 4
// 612.412 us; speedup vs baseline: 1.2072x; 1.2072x over previous
//
#include <hip/hip_runtime.h>

#define N_NODES 100000
#define N_EDGES 1600000
#define N_SCAN_BLOCKS ((N_NODES + 255) / 256)   // 391

// ============ CSR construction (counting sort by dst, atomic-free scatter) ==

__global__ __launch_bounds__(256) void k_hist(const int* __restrict__ ei,
                                              int* __restrict__ cnt,
                                              int* __restrict__ rank)
{
    int e = blockIdx.x * 256 + threadIdx.x;
    if (e >= N_EDGES) return;
    rank[e] = atomicAdd(&cnt[ei[N_EDGES + e]], 1);
}

__global__ __launch_bounds__(256) void k_scan_block(const int* __restrict__ cnt,
                                                    int* __restrict__ row_start,
                                                    int* __restrict__ partial)
{
    __shared__ int s[256];
    int i = blockIdx.x * 256 + threadIdx.x;
    int v = (i < N_NODES) ? cnt[i] : 0;
    s[threadIdx.x] = v;
    __syncthreads();
    for (int off = 1; off < 256; off <<= 1) {
        int t = (threadIdx.x >= off) ? s[threadIdx.x - off] : 0;
        __syncthreads();
        s[threadIdx.x] += t;
        __syncthreads();
    }
    if (i < N_NODES) row_start[i] = s[threadIdx.x] - v;   // exclusive
    if (threadIdx.x == 255) partial[blockIdx.x] = s[255]; // block total
}

__global__ __launch_bounds__(512) void k_scan_top(int* __restrict__ partial)
{
    __shared__ int s[512];
    int v = (threadIdx.x < N_SCAN_BLOCKS) ? partial[threadIdx.x] : 0;
    s[threadIdx.x] = v;
    __syncthreads();
    for (int off = 1; off < 512; off <<= 1) {
        int t = (threadIdx.x >= off) ? s[threadIdx.x - off] : 0;
        __syncthreads();
        s[threadIdx.x] += t;
        __syncthreads();
    }
    if (threadIdx.x < N_SCAN_BLOCKS) partial[threadIdx.x] = s[threadIdx.x] - v;
}

__global__ __launch_bounds__(256) void k_scan_add(int* __restrict__ row_start,
                                                 const int* __restrict__ partial)
{
    int i = blockIdx.x * 256 + threadIdx.x;
    if (i < N_NODES) row_start[i] += partial[i >> 8];
    if (i == 0) row_start[N_NODES] = N_EDGES;
}

__global__ __launch_bounds__(256) void k_scatter(const int* __restrict__ ei,
                                                 const int* __restrict__ row_start,
                                                 const int* __restrict__ rank,
                                                 int* __restrict__ sorted_src)
{
    int e = blockIdx.x * 256 + threadIdx.x;
    if (e >= N_EDGES) return;
    int dst = ei[N_EDGES + e];
    sorted_src[row_start[dst] + rank[e]] = ei[e];
}

// ============ agg1: wave per node, lane = dim ============

__global__ __launch_bounds__(256) void k_agg1(const int* __restrict__ row_start,
                                              const int* __restrict__ sorted_src,
                                              const float* __restrict__ x,
                                              float* __restrict__ agg1)
{
    int node = blockIdx.x * 4 + (threadIdx.x >> 6);
    if (node >= N_NODES) return;
    int d = threadIdx.x & 63;
    int beg = row_start[node], end = row_start[node + 1];
    float a0 = 0.0f, a1 = 0.0f;
    int idx = beg;
    for (; idx + 2 <= end; idx += 2) {
        int s0 = sorted_src[idx];
        int s1 = sorted_src[idx + 1];
        a0 += x[(size_t)s0 * 64 + d];
        a1 += x[(size_t)s1 * 64 + d];
    }
    if (idx < end) a0 += x[(size_t)sorted_src[idx] * 64 + d];
    agg1[(size_t)node * 64 + d] = a0 + a1;
}

// ============ fused node transform: thread per node, LDS-staged weights =====
// h = relu(mean@W1l + x@W1r + b1l);  t2 = h@W2l;  t3 = h@W2r
// All weight reads are wave-uniform LDS broadcasts (conflict-free, no SMEM
// latency chain). h never hits memory.
__global__ __launch_bounds__(128) void k_node(
    const float* __restrict__ x, const float* __restrict__ agg1,
    const int* __restrict__ row_start,
    const float* __restrict__ W1l, const float* __restrict__ b1l,
    const float* __restrict__ W1r, const float* __restrict__ W2l,
    const float* __restrict__ W2r,
    float* __restrict__ t2, float* __restrict__ t3)
{
    __shared__ float sW1l[64 * 64];
    __shared__ float sW1r[64 * 64];
    __shared__ float sW2l[64 * 32];
    __shared__ float sW2r[64 * 32];
    {
        float4* d1 = (float4*)sW1l; const float4* g1 = (const float4*)W1l;
        float4* d2 = (float4*)sW1r; const float4* g2 = (const float4*)W1r;
        for (int i = threadIdx.x; i < 1024; i += 128) { d1[i] = g1[i]; d2[i] = g2[i]; }
        float4* d3 = (float4*)sW2l; const float4* g3 = (const float4*)W2l;
        float4* d4 = (float4*)sW2r; const float4* g4 = (const float4*)W2r;
        for (int i = threadIdx.x; i < 512; i += 128) { d3[i] = g3[i]; d4[i] = g4[i]; }
    }
    __syncthreads();

    int n = blockIdx.x * 128 + threadIdx.x;
    if (n >= N_NODES) return;
    float degf = (float)(row_start[n + 1] - row_start[n]);
    float inv = 1.0f / fmaxf(degf, 1.0f);

    float acc[64];
#pragma unroll
    for (int j = 0; j < 64; j++) acc[j] = b1l[j];

    const float4* av = (const float4*)(agg1 + (size_t)n * 64);
    const float4* xv = (const float4*)(x + (size_t)n * 64);
    for (int kk = 0; kk < 16; kk++) {
        float4 a4 = av[kk];
        float4 x4 = xv[kk];
        float as[4] = {a4.x * inv, a4.y * inv, a4.z * inv, a4.w * inv};
        float xs[4] = {x4.x, x4.y, x4.z, x4.w};
#pragma unroll
        for (int u = 0; u < 4; u++) {
            int k = kk * 4 + u;
            const float4* wl = (const float4*)(sW1l + k * 64);  // uniform addr
            const float4* wr = (const float4*)(sW1r + k * 64);
#pragma unroll
            for (int q = 0; q < 16; q++) {
                float4 l4 = wl[q], r4 = wr[q];
                acc[4*q+0] += as[u] * l4.x + xs[u] * r4.x;
                acc[4*q+1] += as[u] * l4.y + xs[u] * r4.y;
                acc[4*q+2] += as[u] * l4.z + xs[u] * r4.z;
                acc[4*q+3] += as[u] * l4.w + xs[u] * r4.w;
            }
        }
    }

    float o2[32], o3[32];
#pragma unroll
    for (int o = 0; o < 32; o++) { o2[o] = 0.0f; o3[o] = 0.0f; }
#pragma unroll 4
    for (int j = 0; j < 64; j++) {
        float hj = fmaxf(acc[j], 0.0f);
        const float4* w2 = (const float4*)(sW2l + j * 32);     // uniform addr
        const float4* w3 = (const float4*)(sW2r + j * 32);
#pragma unroll
        for (int q = 0; q < 8; q++) {
            float4 a = w2[q], b = w3[q];
            o2[4*q+0] += hj * a.x;  o3[4*q+0] += hj * b.x;
            o2[4*q+1] += hj * a.y;  o3[4*q+1] += hj * b.y;
            o2[4*q+2] += hj * a.z;  o3[4*q+2] += hj * b.z;
            o2[4*q+3] += hj * a.w;  o3[4*q+3] += hj * b.w;
        }
    }
    float4* t2v = (float4*)(t2 + (size_t)n * 32);
    float4* t3v = (float4*)(t3 + (size_t)n * 32);
#pragma unroll
    for (int q = 0; q < 8; q++) {
        t2v[q] = make_float4(o2[4*q], o2[4*q+1], o2[4*q+2], o2[4*q+3]);
        t3v[q] = make_float4(o3[4*q], o3[4*q+1], o3[4*q+2], o3[4*q+3]);
    }
}

// ============ fused agg2 + output: out = (sum t2[src])/deg + t3 + b2l ======
__global__ __launch_bounds__(256) void k_agg2out(
    const int* __restrict__ row_start, const int* __restrict__ sorted_src,
    const float* __restrict__ t2, const float* __restrict__ t3,
    const float* __restrict__ b2l, float* __restrict__ out)
{
    int node = blockIdx.x * 8 + (threadIdx.x >> 5);
    if (node >= N_NODES) return;
    int d = threadIdx.x & 31;
    int beg = row_start[node], end = row_start[node + 1];
    float a0 = 0.0f, a1 = 0.0f;
    int idx = beg;
    for (; idx + 2 <= end; idx += 2) {
        int s0 = sorted_src[idx];
        int s1 = sorted_src[idx + 1];
        a0 += t2[(size_t)s0 * 32 + d];
        a1 += t2[(size_t)s1 * 32 + d];
    }
    if (idx < end) a0 += t2[(size_t)sorted_src[idx] * 32 + d];
    float deg = (float)(end - beg);
    float inv = 1.0f / fmaxf(deg, 1.0f);
    out[(size_t)node * 32 + d] = (a0 + a1) * inv + t3[(size_t)node * 32 + d] + b2l[d];
}

extern "C" void kernel_launch(void* const* d_in, const int* in_sizes, int n_in,
                              void* d_out, int out_size, void* d_ws, size_t ws_size,
                              hipStream_t stream) {
    const float* x   = (const float*)d_in[0];
    const int*   ei  = (const int*)d_in[1];
    const float* W1l = (const float*)d_in[2];
    const float* b1l = (const float*)d_in[3];
    const float* W1r = (const float*)d_in[4];
    const float* W2l = (const float*)d_in[5];
    const float* b2l = (const float*)d_in[6];
    const float* W2r = (const float*)d_in[7];
    float* out = (float*)d_out;

    const size_t N = N_NODES, E = N_EDGES;
    int* wsi = (int*)d_ws;
    int* cnt        = wsi;                     // N
    int* row_start  = wsi + N;                 // N+1
    int* partial    = wsi + 2 * N + 1;         // 512
    int* rank       = wsi + 2 * N + 513;       // E
    int* sorted_src = wsi + 2 * N + 513 + E;   // E
    float* wsf = (float*)(wsi + 2 * N + 513 + 2 * E);
    float* agg1 = wsf;                         // 64N
    float* t2   = wsf + 64 * N;                // 32N
    float* t3   = wsf + 96 * N;                // 32N
    // total: (2N+513+2E)*4 + 128N*4 ~= 65 MB

    hipMemsetAsync(cnt, 0, N * sizeof(int), stream);
    k_hist      <<<(E + 255) / 256, 256, 0, stream>>>(ei, cnt, rank);
    k_scan_block<<<N_SCAN_BLOCKS, 256, 0, stream>>>(cnt, row_start, partial);
    k_scan_top  <<<1, 512, 0, stream>>>(partial);
    k_scan_add  <<<N_SCAN_BLOCKS, 256, 0, stream>>>(row_start, partial);
    k_scatter   <<<(E + 255) / 256, 256, 0, stream>>>(ei, row_start, rank, sorted_src);

    k_agg1   <<<(int)(N / 4), 256, 0, stream>>>(row_start, sorted_src, x, agg1);
    k_node   <<<(int)((N + 127) / 128), 128, 0, stream>>>(x, agg1, row_start,
                                                W1l, b1l, W1r, W2l, W2r, t2, t3);
    k_agg2out<<<(int)(N / 8), 256, 0, stream>>>(row_start, sorted_src, t2, t3, b2l, out);
}

// Round 5
// 430.075 us; speedup vs baseline: 1.7191x; 1.4240x over previous
//
#include <hip/hip_runtime.h>

#define N_NODES 100000
#define N_EDGES 1600000
#define N_SCAN_BLOCKS ((N_NODES + 255) / 256)   // 391

// ============ CSR construction (counting sort by dst, atomic-free scatter) ==

__global__ __launch_bounds__(256) void k_hist(const int* __restrict__ ei,
                                              int* __restrict__ cnt,
                                              int* __restrict__ rank)
{
    int e = blockIdx.x * 256 + threadIdx.x;
    if (e >= N_EDGES) return;
    rank[e] = atomicAdd(&cnt[ei[N_EDGES + e]], 1);
}

__global__ __launch_bounds__(256) void k_scan_block(const int* __restrict__ cnt,
                                                    int* __restrict__ row_start,
                                                    int* __restrict__ partial)
{
    __shared__ int s[256];
    int i = blockIdx.x * 256 + threadIdx.x;
    int v = (i < N_NODES) ? cnt[i] : 0;
    s[threadIdx.x] = v;
    __syncthreads();
    for (int off = 1; off < 256; off <<= 1) {
        int t = (threadIdx.x >= off) ? s[threadIdx.x - off] : 0;
        __syncthreads();
        s[threadIdx.x] += t;
        __syncthreads();
    }
    if (i < N_NODES) row_start[i] = s[threadIdx.x] - v;   // exclusive
    if (threadIdx.x == 255) partial[blockIdx.x] = s[255]; // block total
}

__global__ __launch_bounds__(512) void k_scan_top(int* __restrict__ partial)
{
    __shared__ int s[512];
    int v = (threadIdx.x < N_SCAN_BLOCKS) ? partial[threadIdx.x] : 0;
    s[threadIdx.x] = v;
    __syncthreads();
    for (int off = 1; off < 512; off <<= 1) {
        int t = (threadIdx.x >= off) ? s[threadIdx.x - off] : 0;
        __syncthreads();
        s[threadIdx.x] += t;
        __syncthreads();
    }
    if (threadIdx.x < N_SCAN_BLOCKS) partial[threadIdx.x] = s[threadIdx.x] - v;
}

__global__ __launch_bounds__(256) void k_scan_add(int* __restrict__ row_start,
                                                 const int* __restrict__ partial)
{
    int i = blockIdx.x * 256 + threadIdx.x;
    if (i < N_NODES) row_start[i] += partial[i >> 8];
    if (i == 0) row_start[N_NODES] = N_EDGES;
}

__global__ __launch_bounds__(256) void k_scatter(const int* __restrict__ ei,
                                                 const int* __restrict__ row_start,
                                                 const int* __restrict__ rank,
                                                 int* __restrict__ sorted_src)
{
    int e = blockIdx.x * 256 + threadIdx.x;
    if (e >= N_EDGES) return;
    int dst = ei[N_EDGES + e];
    sorted_src[row_start[dst] + rank[e]] = ei[e];
}

// ============ agg1: wave per node, lane = dim ============

__global__ __launch_bounds__(256) void k_agg1(const int* __restrict__ row_start,
                                              const int* __restrict__ sorted_src,
                                              const float* __restrict__ x,
                                              float* __restrict__ agg1)
{
    int node = blockIdx.x * 4 + (threadIdx.x >> 6);
    if (node >= N_NODES) return;
    int d = threadIdx.x & 63;
    int beg = row_start[node], end = row_start[node + 1];
    float a0 = 0.0f, a1 = 0.0f;
    int idx = beg;
    for (; idx + 2 <= end; idx += 2) {
        int s0 = sorted_src[idx];
        int s1 = sorted_src[idx + 1];
        a0 += x[(size_t)s0 * 64 + d];
        a1 += x[(size_t)s1 * 64 + d];
    }
    if (idx < end) a0 += x[(size_t)sorted_src[idx] * 64 + d];
    agg1[(size_t)node * 64 + d] = a0 + a1;
}

// ============ fused node transform: 4 threads/node, LDS weights, no spill ===
// Thread (n, jg) computes h[n][jg*16 .. jg*16+16) = relu(mean@W1l + x@W1r + b1l),
// then partial t2/t3 (full 32-wide, k-partial over its 16 j's); quad-shuffle
// reduce; each lane stores an 8-wide slice. Live regs ~110 -> no scratch.
__global__ __launch_bounds__(256, 3) void k_node(
    const float* __restrict__ x, const float* __restrict__ agg1,
    const int* __restrict__ row_start,
    const float* __restrict__ W1l, const float* __restrict__ b1l,
    const float* __restrict__ W1r, const float* __restrict__ W2l,
    const float* __restrict__ W2r,
    float* __restrict__ t2, float* __restrict__ t3)
{
    __shared__ float sW1l[64 * 64];
    __shared__ float sW1r[64 * 64];
    __shared__ float sW2l[64 * 32];
    __shared__ float sW2r[64 * 32];
    {
        float4* d1 = (float4*)sW1l; const float4* g1 = (const float4*)W1l;
        float4* d2 = (float4*)sW1r; const float4* g2 = (const float4*)W1r;
        for (int i = threadIdx.x; i < 1024; i += 256) { d1[i] = g1[i]; d2[i] = g2[i]; }
        float4* d3 = (float4*)sW2l; const float4* g3 = (const float4*)W2l;
        float4* d4 = (float4*)sW2r; const float4* g4 = (const float4*)W2r;
        for (int i = threadIdx.x; i < 512; i += 256) { d3[i] = g3[i]; d4[i] = g4[i]; }
    }
    __syncthreads();

    int t = blockIdx.x * 256 + threadIdx.x;
    int n = t >> 2;
    if (n >= N_NODES) return;
    int jg = t & 3;                         // owns h columns [jg*16, jg*16+16)
    float degf = (float)(row_start[n + 1] - row_start[n]);
    float inv = 1.0f / fmaxf(degf, 1.0f);

    float acc[16];
    {
        const float4* bv = (const float4*)(b1l + jg * 16);
#pragma unroll
        for (int q = 0; q < 4; q++) {
            float4 b4 = bv[q];
            acc[4*q+0] = b4.x; acc[4*q+1] = b4.y;
            acc[4*q+2] = b4.z; acc[4*q+3] = b4.w;
        }
    }

    const float4* av = (const float4*)(agg1 + (size_t)n * 64);
    const float4* xv = (const float4*)(x + (size_t)n * 64);
    for (int kk = 0; kk < 16; kk++) {
        float4 a4 = av[kk];
        float4 x4 = xv[kk];
        float as[4] = {a4.x * inv, a4.y * inv, a4.z * inv, a4.w * inv};
        float xs[4] = {x4.x, x4.y, x4.z, x4.w};
#pragma unroll
        for (int u = 0; u < 4; u++) {
            int k = kk * 4 + u;
            const float4* wl = (const float4*)(sW1l + k * 64 + jg * 16);
            const float4* wr = (const float4*)(sW1r + k * 64 + jg * 16);
#pragma unroll
            for (int q = 0; q < 4; q++) {
                float4 l4 = wl[q], r4 = wr[q];
                acc[4*q+0] += as[u] * l4.x + xs[u] * r4.x;
                acc[4*q+1] += as[u] * l4.y + xs[u] * r4.y;
                acc[4*q+2] += as[u] * l4.z + xs[u] * r4.z;
                acc[4*q+3] += as[u] * l4.w + xs[u] * r4.w;
            }
        }
    }

    // second layer: k-partial over this thread's 16 j's, full 32-wide output
    float o2[32], o3[32];
#pragma unroll
    for (int o = 0; o < 32; o++) { o2[o] = 0.0f; o3[o] = 0.0f; }
#pragma unroll 4
    for (int jj = 0; jj < 16; jj++) {
        float hj = fmaxf(acc[jj], 0.0f);
        int j = jg * 16 + jj;
        const float4* w2 = (const float4*)(sW2l + j * 32);
        const float4* w3 = (const float4*)(sW2r + j * 32);
#pragma unroll
        for (int q = 0; q < 8; q++) {
            float4 a = w2[q], b = w3[q];
            o2[4*q+0] += hj * a.x;  o3[4*q+0] += hj * b.x;
            o2[4*q+1] += hj * a.y;  o3[4*q+1] += hj * b.y;
            o2[4*q+2] += hj * a.z;  o3[4*q+2] += hj * b.z;
            o2[4*q+3] += hj * a.w;  o3[4*q+3] += hj * b.w;
        }
    }
    // quad reduce across the 4 lanes of this node
#pragma unroll
    for (int o = 0; o < 32; o++) {
        o2[o] += __shfl_xor(o2[o], 1);
        o2[o] += __shfl_xor(o2[o], 2);
        o3[o] += __shfl_xor(o3[o], 1);
        o3[o] += __shfl_xor(o3[o], 2);
    }
    // lane stores its 8-wide slice; compile-time indices per branch (no
    // dynamic register-array indexing -> no scratch)
    float4* t2v = (float4*)(t2 + (size_t)n * 32 + jg * 8);
    float4* t3v = (float4*)(t3 + (size_t)n * 32 + jg * 8);
    if (jg == 0) {
        t2v[0] = make_float4(o2[0], o2[1], o2[2], o2[3]);
        t2v[1] = make_float4(o2[4], o2[5], o2[6], o2[7]);
        t3v[0] = make_float4(o3[0], o3[1], o3[2], o3[3]);
        t3v[1] = make_float4(o3[4], o3[5], o3[6], o3[7]);
    } else if (jg == 1) {
        t2v[0] = make_float4(o2[8], o2[9], o2[10], o2[11]);
        t2v[1] = make_float4(o2[12], o2[13], o2[14], o2[15]);
        t3v[0] = make_float4(o3[8], o3[9], o3[10], o3[11]);
        t3v[1] = make_float4(o3[12], o3[13], o3[14], o3[15]);
    } else if (jg == 2) {
        t2v[0] = make_float4(o2[16], o2[17], o2[18], o2[19]);
        t2v[1] = make_float4(o2[20], o2[21], o2[22], o2[23]);
        t3v[0] = make_float4(o3[16], o3[17], o3[18], o3[19]);
        t3v[1] = make_float4(o3[20], o3[21], o3[22], o3[23]);
    } else {
        t2v[0] = make_float4(o2[24], o2[25], o2[26], o2[27]);
        t2v[1] = make_float4(o2[28], o2[29], o2[30], o2[31]);
        t3v[0] = make_float4(o3[24], o3[25], o3[26], o3[27]);
        t3v[1] = make_float4(o3[28], o3[29], o3[30], o3[31]);
    }
}

// ============ fused agg2 + output: out = (sum t2[src])/deg + t3 + b2l ======
__global__ __launch_bounds__(256) void k_agg2out(
    const int* __restrict__ row_start, const int* __restrict__ sorted_src,
    const float* __restrict__ t2, const float* __restrict__ t3,
    const float* __restrict__ b2l, float* __restrict__ out)
{
    int node = blockIdx.x * 8 + (threadIdx.x >> 5);
    if (node >= N_NODES) return;
    int d = threadIdx.x & 31;
    int beg = row_start[node], end = row_start[node + 1];
    float a0 = 0.0f, a1 = 0.0f;
    int idx = beg;
    for (; idx + 2 <= end; idx += 2) {
        int s0 = sorted_src[idx];
        int s1 = sorted_src[idx + 1];
        a0 += t2[(size_t)s0 * 32 + d];
        a1 += t2[(size_t)s1 * 32 + d];
    }
    if (idx < end) a0 += t2[(size_t)sorted_src[idx] * 32 + d];
    float deg = (float)(end - beg);
    float inv = 1.0f / fmaxf(deg, 1.0f);
    out[(size_t)node * 32 + d] = (a0 + a1) * inv + t3[(size_t)node * 32 + d] + b2l[d];
}

extern "C" void kernel_launch(void* const* d_in, const int* in_sizes, int n_in,
                              void* d_out, int out_size, void* d_ws, size_t ws_size,
                              hipStream_t stream) {
    const float* x   = (const float*)d_in[0];
    const int*   ei  = (const int*)d_in[1];
    const float* W1l = (const float*)d_in[2];
    const float* b1l = (const float*)d_in[3];
    const float* W1r = (const float*)d_in[4];
    const float* W2l = (const float*)d_in[5];
    const float* b2l = (const float*)d_in[6];
    const float* W2r = (const float*)d_in[7];
    float* out = (float*)d_out;

    const size_t N = N_NODES, E = N_EDGES;
    int* wsi = (int*)d_ws;
    int* cnt        = wsi;                     // N
    int* row_start  = wsi + N;                 // N+1
    int* partial    = wsi + 2 * N + 1;         // 512
    int* rank       = wsi + 2 * N + 513;       // E
    int* sorted_src = wsi + 2 * N + 513 + E;   // E
    float* wsf = (float*)(wsi + 2 * N + 513 + 2 * E);
    float* agg1 = wsf;                         // 64N
    float* t2   = wsf + 64 * N;                // 32N
    float* t3   = wsf + 96 * N;                // 32N
    // total: (2N+513+2E)*4 + 128N*4 ~= 65 MB

    hipMemsetAsync(cnt, 0, N * sizeof(int), stream);
    k_hist      <<<(E + 255) / 256, 256, 0, stream>>>(ei, cnt, rank);
    k_scan_block<<<N_SCAN_BLOCKS, 256, 0, stream>>>(cnt, row_start, partial);
    k_scan_top  <<<1, 512, 0, stream>>>(partial);
    k_scan_add  <<<N_SCAN_BLOCKS, 256, 0, stream>>>(row_start, partial);
    k_scatter   <<<(E + 255) / 256, 256, 0, stream>>>(ei, row_start, rank, sorted_src);

    k_agg1   <<<(int)(N / 4), 256, 0, stream>>>(row_start, sorted_src, x, agg1);
    k_node   <<<(int)((N * 4 + 255) / 256), 256, 0, stream>>>(x, agg1, row_start,
                                                W1l, b1l, W1r, W2l, W2r, t2, t3);
    k_agg2out<<<(int)(N / 8), 256, 0, stream>>>(row_start, sorted_src, t2, t3, b2l, out);
}